// Round 5
// baseline (369.093 us; speedup 1.0000x reference)
//
#include <hip/hip_runtime.h>
#include <hip/hip_bf16.h>
#include <stdint.h>

// Problem constants
#define BB   32
#define CIN  256
#define COUT 256
#define HH   56
#define WW   56
#define HW   3136           // 56*56
#define KEXP 4
#define HP   58             // padded spatial (1-px zero halo)

typedef __attribute__((ext_vector_type(8))) short  short8;
typedef __attribute__((ext_vector_type(4))) float  floatx4;

__device__ __forceinline__ unsigned short f2bf(float f) {
    uint32_t u = __float_as_uint(f);
    u = (u + 0x7fffu + ((u >> 16) & 1u)) >> 16;
    return (unsigned short)u;
}
__device__ __forceinline__ float bf2f(unsigned short s) {
    return __uint_as_float(((uint32_t)s) << 16);
}
__device__ __forceinline__ uint32_t pack2(float a, float b) {
    return (uint32_t)f2bf(a) | ((uint32_t)f2bf(b) << 16);
}

__device__ __forceinline__ void async_copy16(const void* gsrc, void* ldst) {
    __builtin_amdgcn_global_load_lds(
        (const __attribute__((address_space(1))) unsigned int*)gsrc,
        (__attribute__((address_space(3))) unsigned int*)ldst, 16, 0, 0);
}

// ---------------------------------------------------------------------------
// Kernel T: NCHW fp32 -> padded NHWC bf16, plus per-(b,h) pool partials.
// ---------------------------------------------------------------------------
__global__ __launch_bounds__(256) void transpose_pool_kernel(
    const float* __restrict__ x,          // [B][CIN][H][W]
    unsigned short* __restrict__ xt,      // [B][58][58][CIN] bf16, halo zero
    float* __restrict__ partial)          // [B][H][CIN] row sums
{
    __shared__ unsigned short tile[CIN * 62];   // [c][w] stride 62: bank-safe
    const int bx  = blockIdx.x;
    const int b   = bx / HH;
    const int h   = bx % HH;
    const int tid = threadIdx.x;

    const float* xb = x + (size_t)b * CIN * HW + h * WW;

    for (int i = tid; i < CIN * 14; i += 256) {
        const int c  = i / 14;
        const int wv = i % 14;
        const float4 v = *(const float4*)(xb + (size_t)c * HW + wv * 4);
        uint32_t* p = (uint32_t*)&tile[c * 62 + wv * 4];
        p[0] = pack2(v.x, v.y);
        p[1] = pack2(v.z, v.w);
    }
    __syncthreads();

    // per-channel row sum (c = tid)
    {
        float s = 0.f;
        #pragma unroll 8
        for (int i = 0; i < WW; ++i) s += bf2f(tile[tid * 62 + i]);
        partial[((size_t)b * HH + h) * CIN + tid] = s;
    }

    // padded NHWC write, 2 channels per lane (4 B stores)
    unsigned short* row = xt + (((size_t)b * HP + (h + 1)) * HP) * CIN;
    for (int j = tid; j < WW * 128; j += 256) {
        const int w  = j >> 7;
        const int c2 = (j & 127) * 2;
        const uint32_t v = (uint32_t)tile[c2 * 62 + w]
                         | ((uint32_t)tile[(c2 + 1) * 62 + w] << 16);
        *(uint32_t*)&row[(w + 1) * CIN + c2] = v;
    }

    // halo: w'=0 and w'=57 of this row
    if (tid < 128) {
        ((uint32_t*)&row[0])[tid]          = 0u;
        ((uint32_t*)&row[57 * CIN])[tid]   = 0u;
    }
    // halo: full rows h'=0 and h'=57 (only h==0 blocks)
    if (h == 0) {
        uint32_t* r0  = (uint32_t*)(xt + ((size_t)b * HP + 0)  * HP * CIN);
        uint32_t* r57 = (uint32_t*)(xt + ((size_t)b * HP + 57) * HP * CIN);
        for (int i = tid; i < HP * 128; i += 256) { r0[i] = 0u; r57[i] = 0u; }
    }
}

// ---------------------------------------------------------------------------
// Kernel A: pool-partial reduce + attention MLP + softmax -> att[B][K]
// ---------------------------------------------------------------------------
__global__ __launch_bounds__(256) void attn_kernel(
    const float* __restrict__ partial,  // [B][H][CIN]
    const float* __restrict__ fc1w,     // [K][CIN]
    const float* __restrict__ fc1b,     // [K]
    const float* __restrict__ fc2w,     // [K][K]
    const float* __restrict__ fc2b,     // [K]
    float* __restrict__ att)            // [B][K]
{
    __shared__ float pl[CIN];
    const int b   = blockIdx.x;
    const int tid = threadIdx.x;

    float s = 0.f;
    const float* pp = partial + (size_t)b * HH * CIN + tid;
    #pragma unroll 8
    for (int h = 0; h < HH; ++h) s += pp[h * CIN];
    pl[tid] = s * (1.0f / (float)HW);
    __syncthreads();

    if (tid < 64) {
        const int lane = tid;
        float sk[KEXP] = {0.f, 0.f, 0.f, 0.f};
        #pragma unroll
        for (int c0 = 0; c0 < CIN; c0 += 64) {
            const float p = pl[c0 + lane];
            #pragma unroll
            for (int k = 0; k < KEXP; ++k) sk[k] += p * fc1w[k * CIN + c0 + lane];
        }
        #pragma unroll
        for (int off = 32; off > 0; off >>= 1) {
            #pragma unroll
            for (int k = 0; k < KEXP; ++k) sk[k] += __shfl_down(sk[k], off);
        }
        if (lane == 0) {
            float a[KEXP];
            #pragma unroll
            for (int k = 0; k < KEXP; ++k) a[k] = fmaxf(sk[k] + fc1b[k], 0.f);
            float z[KEXP], m = -1e30f;
            #pragma unroll
            for (int j = 0; j < KEXP; ++j) {
                float t = fc2b[j];
                #pragma unroll
                for (int k = 0; k < KEXP; ++k) t += a[k] * fc2w[j * KEXP + k];
                z[j] = t;
                m = fmaxf(m, t);
            }
            float den = 0.f;
            #pragma unroll
            for (int j = 0; j < KEXP; ++j) { z[j] = expf(z[j] - m); den += z[j]; }
            const float inv = 1.0f / den;
            #pragma unroll
            for (int j = 0; j < KEXP; ++j) att[b * KEXP + j] = z[j] * inv;
        }
    }
}

// ---------------------------------------------------------------------------
// Kernel W: aggregate expert weights -> agg_w[b][rs][o][c] (bf16), agg_b[b][o]
// ---------------------------------------------------------------------------
__global__ __launch_bounds__(256) void aggw_kernel(
    const float* __restrict__ weight,   // [K][COUT][CIN][3][3]
    const float* __restrict__ bias,     // [K][COUT]
    const float* __restrict__ att,      // [B][K]
    unsigned short* __restrict__ aggw,  // [B][9][COUT][CIN] bf16
    float* __restrict__ aggb)           // [B][COUT]
{
    __shared__ float accw[CIN * 9];     // staging for (c,rs)->(rs,c) transpose
    const int bx  = blockIdx.x;
    const int o   = bx >> 2;
    const int b0  = (bx & 3) * 8;
    const int tid = threadIdx.x;

    float wreg[KEXP][9];
    #pragma unroll
    for (int k = 0; k < KEXP; ++k) {
        const float* wk = weight + (size_t)(k * COUT + o) * (CIN * 9);
        #pragma unroll
        for (int j = 0; j < 9; ++j) wreg[k][j] = wk[j * 256 + tid];
    }
    float bvals[KEXP];
    #pragma unroll
    for (int k = 0; k < KEXP; ++k) bvals[k] = bias[k * COUT + o];

    for (int bi = 0; bi < 8; ++bi) {
        const int b = b0 + bi;
        float av[KEXP];
        #pragma unroll
        for (int k = 0; k < KEXP; ++k) av[k] = att[b * KEXP + k];

        __syncthreads();   // previous iteration's accw reads complete
        #pragma unroll
        for (int j = 0; j < 9; ++j) {
            float r = 0.f;
            #pragma unroll
            for (int k = 0; k < KEXP; ++k) r += av[k] * wreg[k][j];
            accw[j * 256 + tid] = r;   // accw[flat] mirrors weight-flat layout
        }
        __syncthreads();

        // element (c, rs) = accw[c*9 + rs]; write [rs][c] packed pairs
        for (int i = tid; i < 9 * 128; i += 256) {
            const int j  = i >> 7;          // rs
            const int cp = (i & 127) * 2;   // channel pair
            const uint32_t v = pack2(accw[cp * 9 + j], accw[(cp + 1) * 9 + j]);
            *(uint32_t*)&aggw[(((size_t)b * 9 + j) * COUT + o) * CIN + cp] = v;
        }
        if (tid == 0) {
            float sb = 0.f;
            #pragma unroll
            for (int k = 0; k < KEXP; ++k) sb += av[k] * bvals[k];
            aggb[b * COUT + o] = sb;
        }
    }
}

// ---------------------------------------------------------------------------
// Kernel G: per-sample implicit-im2col GEMM, 256x256 tile.
//
// ROUND 5: minimum-2-phase pipeline — ONE barrier per K-tile (was 2).
// R4 post-mortem: per-block time 68 us vs 37 us MFMA floor (55% in-block
// efficiency). Residual suspects: the mid-tile 8-wave join (only needed
// for ks0 overwrite safety under the 1.5-tile lookahead) and the end
// vmcnt(4) waiting on loads issued only ~half a tile earlier.
//
// New per-tile schedule (full-tile parity double buffer):
//   [stage ALL of tile t+1 -> buf (t+1)&1 : 8 global_load_lds]  SB0
//   [24 ds_read_b128 + 64 MFMA, UNPINNED -- compiler interleaves with
//    its own counted lgkmcnt]
//   SB0  s_waitcnt vmcnt(0)  s_barrier  SB0
// - vmcnt(0) has a full-tile issue-to-wait gap (~2500 cy >> ~900 cy HBM
//   latency): effectively a fully-slack counted wait.
// - Safety is ordering-based: tile-t reads are consumed by MFMAs
//   (auto-lgkm) that are SB0-pinned above the end barrier, so every
//   wave's reads COMPLETE before any wave passes the bar; stages for
//   t+2 issue only after that bar and target the opposite buffer.
// ---------------------------------------------------------------------------
#define MM(AB, AF, BF) do {                                                    \
    __builtin_amdgcn_s_setprio(1);                                             \
    _Pragma("unroll")                                                          \
    for (int mi_ = 0; mi_ < 4; ++mi_)                                          \
        _Pragma("unroll")                                                      \
        for (int ni_ = 0; ni_ < 4; ++ni_)                                      \
            acc[(AB) + mi_][ni_] = __builtin_amdgcn_mfma_f32_16x16x32_bf16(    \
                AF[mi_], BF[ni_], acc[(AB) + mi_][ni_], 0, 0, 0);              \
    __builtin_amdgcn_s_setprio(0);                                             \
} while (0)

// reads + 4 MM phases for the tile in buffer BUFOFF (numerics == R4)
#define TILE_COMPUTE(BUFOFF) do {                                              \
    const char* A0_ = lds + (BUFOFF) + lnoff;                                  \
    const char* B0_ = lds + (BUFOFF) + 32768 + lnoff;                          \
    short8 a0[4], a1[4], a2[4], a3[4], b0[4], b1[4];                           \
    _Pragma("unroll")                                                          \
    for (int i_ = 0; i_ < 4; ++i_)                                             \
        b0[i_] = *(const short8*)(B0_ + wn * 4096 + i_ * 1024);                \
    _Pragma("unroll")                                                          \
    for (int i_ = 0; i_ < 4; ++i_)                                             \
        a0[i_] = *(const short8*)(A0_ + wm * 8192 + i_ * 1024);                \
    MM(0, a0, b0);                                                             \
    _Pragma("unroll")                                                          \
    for (int i_ = 0; i_ < 4; ++i_)                                             \
        a1[i_] = *(const short8*)(A0_ + wm * 8192 + 4096 + i_ * 1024);         \
    MM(4, a1, b0);                                                             \
    _Pragma("unroll")                                                          \
    for (int i_ = 0; i_ < 4; ++i_)                                             \
        b1[i_] = *(const short8*)(B0_ + 16384 + wn * 4096 + i_ * 1024);        \
    _Pragma("unroll")                                                          \
    for (int i_ = 0; i_ < 4; ++i_)                                             \
        a2[i_] = *(const short8*)(A0_ + 16384 + wm * 8192 + 4096 + i_ * 1024); \
    MM(4, a2, b1);                                                             \
    _Pragma("unroll")                                                          \
    for (int i_ = 0; i_ < 4; ++i_)                                             \
        a3[i_] = *(const short8*)(A0_ + 16384 + wm * 8192 + i_ * 1024);        \
    MM(0, a3, b1);                                                             \
} while (0)

__global__ __launch_bounds__(512, 2) void conv_gemm_kernel(
    const unsigned short* __restrict__ xt,    // [B][58][58][CIN] bf16 padded
    const unsigned short* __restrict__ aggw,  // [B][9][COUT][CIN] bf16
    const float* __restrict__ aggb,           // [B][COUT]
    float* __restrict__ out)                  // [B][COUT][HW]
{
    __shared__ __attribute__((aligned(128))) char lds[131072];

    // grid 416 = 32 b x 13 n-tiles; bijective XCD chunking (416 % 8 == 0).
    const int bx = blockIdx.x;
    const int wg = (bx & 7) * 52 + (bx >> 3);
    const int b  = wg / 13;
    const int p0 = (wg - b * 13) * 256;

    const int tid  = threadIdx.x;
    const int wave = tid >> 6;
    const int lane = tid & 63;
    const int wm   = wave >> 2;                 // 0..1 (M half)
    const int wn   = wave & 3;                  // 0..3 (N quarter)
    const int m    = lane & 15;
    const int q    = lane >> 4;                 // 0..3 k-chunk of fragment
    const int lnoff = m * 64 + ((q ^ (m >> 1)) & 3) * 16;  // read swizzle

    const char* aggw_b = (const char*)aggw + (size_t)b * (9 * COUT * CIN * 2);
    const char* xt_b   = (const char*)xt   + (size_t)b * (HP * HP * CIN * 2);

    // staging geometry: unit n = j*512 + tid; row r = n>>2; chunk u = n&3
    int aoff0, aoff1, boff0, boff1;
    {
        int n = tid, r = n >> 2, u = n & 3, sw = (u ^ (r >> 1)) & 3;
        aoff0 = r * 512 + sw * 16;
        int p = p0 + r; int pv = (p < HW) ? p : 0;
        int h = pv / WW, w = pv - h * WW;
        boff0 = ((h + 1) * HP + (w + 1)) * 512 + sw * 16;

        n = 512 + tid; r = n >> 2; u = n & 3; sw = (u ^ (r >> 1)) & 3;
        aoff1 = r * 512 + sw * 16;
        p = p0 + r; pv = (p < HW) ? p : 0;
        h = pv / WW; w = pv - h * WW;
        boff1 = ((h + 1) * HP + (w + 1)) * 512 + sw * 16;
    }

    auto stageA = [&](int kt, int ks) {
        const int ga = (kt >> 2) * (COUT * CIN * 2) + (kt & 3) * 128 + ks * 64;
        char* d = lds + (kt & 1) * 65536 + ks * 16384 + wave * 1024;
        async_copy16(aggw_b + (size_t)(ga + aoff0), d);
        async_copy16(aggw_b + (size_t)(ga + aoff1), d + 8192);
    };
    auto stageB = [&](int kt, int ks) {
        const int rs = kt >> 2;
        const int gb = ((rs / 3 - 1) * HP + (rs % 3 - 1)) * 512
                     + (kt & 3) * 128 + ks * 64;
        char* d = lds + (kt & 1) * 65536 + 32768 + ks * 16384 + wave * 1024;
        async_copy16(xt_b + (size_t)(gb + boff0), d);
        async_copy16(xt_b + (size_t)(gb + boff1), d + 8192);
    };

    floatx4 acc[8][4];
    #pragma unroll
    for (int a_ = 0; a_ < 8; ++a_)
        #pragma unroll
        for (int n_ = 0; n_ < 4; ++n_)
            #pragma unroll
            for (int e_ = 0; e_ < 4; ++e_) acc[a_][n_][e_] = 0.f;

    // Prologue: stage tile 0 fully into buf 0, drain, join.
    stageA(0, 0); stageB(0, 0);
    stageA(0, 1); stageB(0, 1);
    __builtin_amdgcn_sched_barrier(0);
    asm volatile("s_waitcnt vmcnt(0)");
    __builtin_amdgcn_s_barrier();
    __builtin_amdgcn_sched_barrier(0);

    // 36 K-tiles (9 taps x 4 channel-blocks); tile 35 peeled (no stage).
    #pragma unroll 1
    for (int t = 0; t < 35; ++t) {
        const int nt = t + 1;
        // stage ALL of tile t+1 into the opposite buffer (8 loads/thread)
        stageA(nt, 0); stageB(nt, 0);
        stageA(nt, 1); stageB(nt, 1);
        __builtin_amdgcn_sched_barrier(0);   // pin stages at tile top

        TILE_COMPUTE((t & 1) * 65536);

        __builtin_amdgcn_sched_barrier(0);   // MFMA stay above the wait
        asm volatile("s_waitcnt vmcnt(0)");  // full-tile slack: t+1 landed
        __builtin_amdgcn_s_barrier();
        __builtin_amdgcn_sched_barrier(0);
    }
    // tile 35 (buf 1): compute only
    TILE_COMPUTE(65536);

    // Epilogue: C/D layout col = lane&15 (pixel), row = (lane>>4)*4 + e (o)
    float* outb = out + (size_t)b * COUT * HW;
    const int g4 = q * 4;
    #pragma unroll
    for (int am = 0; am < 8; ++am) {
        const int o = wm * 128 + am * 16 + g4;
        #pragma unroll
        for (int e = 0; e < 4; ++e) {
            const float bv = aggb[b * COUT + o + e];
            #pragma unroll
            for (int ni = 0; ni < 4; ++ni) {
                const int p = p0 + wn * 64 + ni * 16 + m;
                if (p < HW) outb[(size_t)(o + e) * HW + p] = acc[am][ni][e] + bv;
            }
        }
    }
}

// ---------------------------------------------------------------------------
// Launch
// ---------------------------------------------------------------------------
extern "C" void kernel_launch(void* const* d_in, const int* in_sizes, int n_in,
                              void* d_out, int out_size, void* d_ws, size_t ws_size,
                              hipStream_t stream) {
    const float* x      = (const float*)d_in[0];
    const float* weight = (const float*)d_in[1];
    const float* bias   = (const float*)d_in[2];
    const float* fc1w   = (const float*)d_in[3];
    const float* fc1b   = (const float*)d_in[4];
    const float* fc2w   = (const float*)d_in[5];
    const float* fc2b   = (const float*)d_in[6];
    float* out = (float*)d_out;

    char* ws = (char*)d_ws;
    // workspace layout (256 B aligned)
    unsigned short* xt      = (unsigned short*)(ws);              // 55,115,776 B
    unsigned short* aggw    = (unsigned short*)(ws + 55115776);   // 37,748,736 B
    float*          partial = (float*)(ws + 92864512);            //  1,835,008 B
    float*          att     = (float*)(ws + 94699520);            //        512 B
    float*          aggb    = (float*)(ws + 94700032);            //     32,768 B

    transpose_pool_kernel<<<BB * HH, 256, 0, stream>>>(x, xt, partial);
    attn_kernel<<<BB, 256, 0, stream>>>(partial, fc1w, fc1b, fc2w, fc2b, att);
    aggw_kernel<<<COUT * 4, 256, 0, stream>>>(weight, bias, att, aggw, aggb);
    conv_gemm_kernel<<<BB * 13, 512, 0, stream>>>(xt, aggw, aggb, out);
}

// Round 7
// 351.092 us; speedup vs baseline: 1.0513x; 1.0513x over previous
//
#include <hip/hip_runtime.h>
#include <hip/hip_bf16.h>
#include <stdint.h>

// Problem constants
#define BB   32
#define CIN  256
#define COUT 256
#define HH   56
#define WW   56
#define HW   3136           // 56*56
#define KEXP 4
#define HP   58             // padded spatial (1-px zero halo)

typedef __attribute__((ext_vector_type(8))) short  short8;
typedef __attribute__((ext_vector_type(4))) float  floatx4;

__device__ __forceinline__ unsigned short f2bf(float f) {
    uint32_t u = __float_as_uint(f);
    u = (u + 0x7fffu + ((u >> 16) & 1u)) >> 16;
    return (unsigned short)u;
}
__device__ __forceinline__ float bf2f(unsigned short s) {
    return __uint_as_float(((uint32_t)s) << 16);
}
__device__ __forceinline__ uint32_t pack2(float a, float b) {
    return (uint32_t)f2bf(a) | ((uint32_t)f2bf(b) << 16);
}

__device__ __forceinline__ void async_copy16(const void* gsrc, void* ldst) {
    __builtin_amdgcn_global_load_lds(
        (const __attribute__((address_space(1))) unsigned int*)gsrc,
        (__attribute__((address_space(3))) unsigned int*)ldst, 16, 0, 0);
}

// ---------------------------------------------------------------------------
// Kernel T: NCHW fp32 -> padded NHWC bf16, plus per-(b,h) pool partials.
// ---------------------------------------------------------------------------
__global__ __launch_bounds__(256) void transpose_pool_kernel(
    const float* __restrict__ x,          // [B][CIN][H][W]
    unsigned short* __restrict__ xt,      // [B][58][58][CIN] bf16, halo zero
    float* __restrict__ partial)          // [B][H][CIN] row sums
{
    __shared__ unsigned short tile[CIN * 62];   // [c][w] stride 62: bank-safe
    const int bx  = blockIdx.x;
    const int b   = bx / HH;
    const int h   = bx % HH;
    const int tid = threadIdx.x;

    const float* xb = x + (size_t)b * CIN * HW + h * WW;

    for (int i = tid; i < CIN * 14; i += 256) {
        const int c  = i / 14;
        const int wv = i % 14;
        const float4 v = *(const float4*)(xb + (size_t)c * HW + wv * 4);
        uint32_t* p = (uint32_t*)&tile[c * 62 + wv * 4];
        p[0] = pack2(v.x, v.y);
        p[1] = pack2(v.z, v.w);
    }
    __syncthreads();

    // per-channel row sum (c = tid)
    {
        float s = 0.f;
        #pragma unroll 8
        for (int i = 0; i < WW; ++i) s += bf2f(tile[tid * 62 + i]);
        partial[((size_t)b * HH + h) * CIN + tid] = s;
    }

    // padded NHWC write, 2 channels per lane (4 B stores)
    unsigned short* row = xt + (((size_t)b * HP + (h + 1)) * HP) * CIN;
    for (int j = tid; j < WW * 128; j += 256) {
        const int w  = j >> 7;
        const int c2 = (j & 127) * 2;
        const uint32_t v = (uint32_t)tile[c2 * 62 + w]
                         | ((uint32_t)tile[(c2 + 1) * 62 + w] << 16);
        *(uint32_t*)&row[(w + 1) * CIN + c2] = v;
    }

    // halo: w'=0 and w'=57 of this row
    if (tid < 128) {
        ((uint32_t*)&row[0])[tid]          = 0u;
        ((uint32_t*)&row[57 * CIN])[tid]   = 0u;
    }
    // halo: full rows h'=0 and h'=57 (only h==0 blocks)
    if (h == 0) {
        uint32_t* r0  = (uint32_t*)(xt + ((size_t)b * HP + 0)  * HP * CIN);
        uint32_t* r57 = (uint32_t*)(xt + ((size_t)b * HP + 57) * HP * CIN);
        for (int i = tid; i < HP * 128; i += 256) { r0[i] = 0u; r57[i] = 0u; }
    }
}

// ---------------------------------------------------------------------------
// Kernel A: pool-partial reduce + attention MLP + softmax -> att[B][K]
// ---------------------------------------------------------------------------
__global__ __launch_bounds__(256) void attn_kernel(
    const float* __restrict__ partial,  // [B][H][CIN]
    const float* __restrict__ fc1w,     // [K][CIN]
    const float* __restrict__ fc1b,     // [K]
    const float* __restrict__ fc2w,     // [K][K]
    const float* __restrict__ fc2b,     // [K]
    float* __restrict__ att)            // [B][K]
{
    __shared__ float pl[CIN];
    const int b   = blockIdx.x;
    const int tid = threadIdx.x;

    float s = 0.f;
    const float* pp = partial + (size_t)b * HH * CIN + tid;
    #pragma unroll 8
    for (int h = 0; h < HH; ++h) s += pp[h * CIN];
    pl[tid] = s * (1.0f / (float)HW);
    __syncthreads();

    if (tid < 64) {
        const int lane = tid;
        float sk[KEXP] = {0.f, 0.f, 0.f, 0.f};
        #pragma unroll
        for (int c0 = 0; c0 < CIN; c0 += 64) {
            const float p = pl[c0 + lane];
            #pragma unroll
            for (int k = 0; k < KEXP; ++k) sk[k] += p * fc1w[k * CIN + c0 + lane];
        }
        #pragma unroll
        for (int off = 32; off > 0; off >>= 1) {
            #pragma unroll
            for (int k = 0; k < KEXP; ++k) sk[k] += __shfl_down(sk[k], off);
        }
        if (lane == 0) {
            float a[KEXP];
            #pragma unroll
            for (int k = 0; k < KEXP; ++k) a[k] = fmaxf(sk[k] + fc1b[k], 0.f);
            float z[KEXP], m = -1e30f;
            #pragma unroll
            for (int j = 0; j < KEXP; ++j) {
                float t = fc2b[j];
                #pragma unroll
                for (int k = 0; k < KEXP; ++k) t += a[k] * fc2w[j * KEXP + k];
                z[j] = t;
                m = fmaxf(m, t);
            }
            float den = 0.f;
            #pragma unroll
            for (int j = 0; j < KEXP; ++j) { z[j] = expf(z[j] - m); den += z[j]; }
            const float inv = 1.0f / den;
            #pragma unroll
            for (int j = 0; j < KEXP; ++j) att[b * KEXP + j] = z[j] * inv;
        }
    }
}

// ---------------------------------------------------------------------------
// Kernel W: aggregate expert weights -> agg_w[b][rs][o][c] (bf16), agg_b[b][o]
// ---------------------------------------------------------------------------
__global__ __launch_bounds__(256) void aggw_kernel(
    const float* __restrict__ weight,   // [K][COUT][CIN][3][3]
    const float* __restrict__ bias,     // [K][COUT]
    const float* __restrict__ att,      // [B][K]
    unsigned short* __restrict__ aggw,  // [B][9][COUT][CIN] bf16
    float* __restrict__ aggb)           // [B][COUT]
{
    __shared__ float accw[CIN * 9];     // staging for (c,rs)->(rs,c) transpose
    const int bx  = blockIdx.x;
    const int o   = bx >> 2;
    const int b0  = (bx & 3) * 8;
    const int tid = threadIdx.x;

    float wreg[KEXP][9];
    #pragma unroll
    for (int k = 0; k < KEXP; ++k) {
        const float* wk = weight + (size_t)(k * COUT + o) * (CIN * 9);
        #pragma unroll
        for (int j = 0; j < 9; ++j) wreg[k][j] = wk[j * 256 + tid];
    }
    float bvals[KEXP];
    #pragma unroll
    for (int k = 0; k < KEXP; ++k) bvals[k] = bias[k * COUT + o];

    for (int bi = 0; bi < 8; ++bi) {
        const int b = b0 + bi;
        float av[KEXP];
        #pragma unroll
        for (int k = 0; k < KEXP; ++k) av[k] = att[b * KEXP + k];

        __syncthreads();   // previous iteration's accw reads complete
        #pragma unroll
        for (int j = 0; j < 9; ++j) {
            float r = 0.f;
            #pragma unroll
            for (int k = 0; k < KEXP; ++k) r += av[k] * wreg[k][j];
            accw[j * 256 + tid] = r;   // accw[flat] mirrors weight-flat layout
        }
        __syncthreads();

        // element (c, rs) = accw[c*9 + rs]; write [rs][c] packed pairs
        for (int i = tid; i < 9 * 128; i += 256) {
            const int j  = i >> 7;          // rs
            const int cp = (i & 127) * 2;   // channel pair
            const uint32_t v = pack2(accw[cp * 9 + j], accw[(cp + 1) * 9 + j]);
            *(uint32_t*)&aggw[(((size_t)b * 9 + j) * COUT + o) * CIN + cp] = v;
        }
        if (tid == 0) {
            float sb = 0.f;
            #pragma unroll
            for (int k = 0; k < KEXP; ++k) sb += av[k] * bvals[k];
            aggb[b * COUT + o] = sb;
        }
    }
}

// ---------------------------------------------------------------------------
// Kernel G: per-sample implicit-im2col GEMM.
//
// ROUND 6 (resubmitted after infra failure): re-geometry for 2 blocks/CU.
// R0-R5 post-mortem: three schedules (8-phase, 2-bar counted, 1-bar drain)
// all land at 29-35% MfmaUtil because the 256x256/128KB-LDS block pins the
// CU to ONE block = 2 lockstep waves per SIMD: every stall is exposed.
// m97's implicit overlap needs independent co-resident blocks.
//
// New geometry: BM=256 x BN=128, BK=32, 512 thr, 8 waves (4M x 2N),
// per-wave 64x64 -> acc = 64 VGPR.  __launch_bounds__(512,4) caps VGPR
// <=128 -> 4 waves/SIMD.  LDS: A 16KB + B 8KB = 24KB/buffer x 3 buffers
// = 72KB -> TWO blocks/CU (144KB), 16 waves/CU, barrier-independent.
// 3-buffer rotation gives a 2-tile prefetch lookahead with counted
// vmcnt(3) at each tile end (t+1 landed, t+2 in flight) -- never drains.
// Grid 800 = 32 b x 25 ptiles (800%8==0 bijective XCD chunk; 4 samples
// per XCD for L2 locality).  72 K-tiles (9 taps x 8 ch-blocks of 32).
// Swizzle algebra (lnoff / staging involution) identical to the verified
// R0-R5 kernels; only row counts and strides changed.
// ---------------------------------------------------------------------------
#define TILE_COMPUTE(BUFOFF) do {                                              \
    const char* A_ = lds + (BUFOFF) + lnoff;                                   \
    const char* B_ = lds + (BUFOFF) + 16384 + lnoff;                           \
    short8 af[4], bf[4];                                                       \
    _Pragma("unroll")                                                          \
    for (int ni_ = 0; ni_ < 4; ++ni_)                                          \
        bf[ni_] = *(const short8*)(B_ + wn * 4096 + ni_ * 1024);               \
    _Pragma("unroll")                                                          \
    for (int mi_ = 0; mi_ < 4; ++mi_)                                          \
        af[mi_] = *(const short8*)(A_ + wm * 4096 + mi_ * 1024);               \
    __builtin_amdgcn_s_setprio(1);                                             \
    _Pragma("unroll")                                                          \
    for (int mi_ = 0; mi_ < 4; ++mi_)                                          \
        _Pragma("unroll")                                                      \
        for (int ni_ = 0; ni_ < 4; ++ni_)                                      \
            acc[mi_][ni_] = __builtin_amdgcn_mfma_f32_16x16x32_bf16(           \
                af[mi_], bf[ni_], acc[mi_][ni_], 0, 0, 0);                     \
    __builtin_amdgcn_s_setprio(0);                                             \
} while (0)

#define STEP(TBUF, STAGE_STMT, VM_STMT) do {                                   \
    STAGE_STMT;                                                                \
    __builtin_amdgcn_sched_barrier(0);                                         \
    TILE_COMPUTE(TBUF);                                                        \
    __builtin_amdgcn_sched_barrier(0);                                         \
    VM_STMT;                                                                   \
    __builtin_amdgcn_s_barrier();                                              \
    __builtin_amdgcn_sched_barrier(0);                                         \
} while (0)

__global__ __launch_bounds__(512, 4) void conv_gemm_kernel(
    const unsigned short* __restrict__ xt,    // [B][58][58][CIN] bf16 padded
    const unsigned short* __restrict__ aggw,  // [B][9][COUT][CIN] bf16
    const float* __restrict__ aggb,           // [B][COUT]
    float* __restrict__ out)                  // [B][COUT][HW]
{
    __shared__ __attribute__((aligned(128))) char lds[73728];   // 3 x 24KB

    // grid 800 = 32 b x 25 n-tiles; bijective XCD chunking (800 % 8 == 0):
    // XCD x owns wg in [x*100, (x+1)*100) = exactly 4 consecutive samples.
    const int bx = blockIdx.x;
    const int wg = (bx & 7) * 100 + (bx >> 3);
    const int b  = wg / 25;
    const int p0 = (wg - b * 25) * 128;

    const int tid  = threadIdx.x;
    const int wave = tid >> 6;
    const int lane = tid & 63;
    const int wm   = wave >> 1;                 // 0..3 (M quarter, 64 rows)
    const int wn   = wave & 1;                  // 0..1 (N half, 64 cols)
    const int m    = lane & 15;
    const int q    = lane >> 4;                 // 0..3 k-chunk of fragment
    const int lnoff = m * 64 + ((q ^ (m >> 1)) & 3) * 16;  // read swizzle

    const char* aggw_b = (const char*)aggw + (size_t)b * (9 * COUT * CIN * 2);
    const char* xt_b   = (const char*)xt   + (size_t)b * (HP * HP * CIN * 2);

    // staging geometry: unit n -> row r = n>>2, chunk u = n&3,
    // inverse-swizzled source chunk sw = (u ^ (r>>1)) & 3 (involution).
    // A rows 0..255 via n = tid and n = 512+tid; B rows 0..127 via n = tid.
    int aoff0, aoff1, boff0;
    {
        int n = tid, r = n >> 2, u = n & 3, sw = (u ^ (r >> 1)) & 3;
        aoff0 = r * 512 + sw * 16;

        n = 512 + tid; r = n >> 2; u = n & 3; sw = (u ^ (r >> 1)) & 3;
        aoff1 = r * 512 + sw * 16;

        n = tid; r = n >> 2; u = n & 3; sw = (u ^ (r >> 1)) & 3;
        int p = p0 + r; int pv = (p < HW) ? p : 0;
        int h = pv / WW, w = pv - h * WW;
        boff0 = ((h + 1) * HP + (w + 1)) * 512 + sw * 16;
    }

    // stage tile kt (rs = kt/8 tap, c0 = (kt%8)*32 channels) into buffer BUF.
    // 3 loads/thread: A rows 0..127, A rows 128..255, B rows 0..127.
    auto stage = [&](int kt, char* buf) {
        const int rs = kt >> 3;
        const int c2 = (kt & 7) * 64;                   // c0 * 2 bytes
        const int ga = rs * (COUT * CIN * 2) + c2;
        const int gb = ((rs / 3 - 1) * HP + (rs % 3 - 1)) * 512 + c2;
        char* dA = buf + wave * 1024;
        async_copy16(aggw_b + (size_t)(ga + aoff0), dA);
        async_copy16(aggw_b + (size_t)(ga + aoff1), dA + 8192);
        async_copy16(xt_b   + (size_t)(gb + boff0), buf + 16384 + wave * 1024);
    };

    floatx4 acc[4][4];
    #pragma unroll
    for (int a_ = 0; a_ < 4; ++a_)
        #pragma unroll
        for (int n_ = 0; n_ < 4; ++n_)
            #pragma unroll
            for (int e_ = 0; e_ < 4; ++e_) acc[a_][n_][e_] = 0.f;

    // Prologue: stage tiles 0,1 (6 loads); vmcnt(3) -> tile 0 landed.
    stage(0, lds);
    stage(1, lds + 24576);
    __builtin_amdgcn_sched_barrier(0);
    asm volatile("s_waitcnt vmcnt(3)");
    __builtin_amdgcn_s_barrier();
    __builtin_amdgcn_sched_barrier(0);

    // 72 K-tiles; buffers rotate t%3; stage t+2 at top of t; counted
    // vmcnt(3) at each tile end (outstanding: t+1's 3 + t+2's 3 -> wait
    // leaves t+2's 3 => t+1 fully landed). Last iteration peeled.
    #pragma unroll 1
    for (int i = 0; i < 23; ++i) {
        const int t = 3 * i;
        STEP(0,     stage(t + 2, lds + 49152), asm volatile("s_waitcnt vmcnt(3)"));
        STEP(24576, stage(t + 3, lds),         asm volatile("s_waitcnt vmcnt(3)"));
        STEP(49152, stage(t + 4, lds + 24576), asm volatile("s_waitcnt vmcnt(3)"));
    }
    // tiles 69, 70, 71
    STEP(0,     stage(71, lds + 49152), asm volatile("s_waitcnt vmcnt(3)"));
    STEP(24576, ((void)0),              asm volatile("s_waitcnt vmcnt(0)"));
    TILE_COMPUTE(49152);

    // Epilogue: C/D layout col = lane&15 (pixel), row = (lane>>4)*4 + e (o)
    float* outb = out + (size_t)b * COUT * HW;
    const int g4 = q * 4;
    #pragma unroll
    for (int mi = 0; mi < 4; ++mi) {
        const int o = wm * 64 + mi * 16 + g4;
        #pragma unroll
        for (int e = 0; e < 4; ++e) {
            const float bv = aggb[b * COUT + o + e];
            #pragma unroll
            for (int ni = 0; ni < 4; ++ni) {
                const int p = p0 + wn * 64 + ni * 16 + m;
                if (p < HW) outb[(size_t)(o + e) * HW + p] = acc[mi][ni][e] + bv;
            }
        }
    }
}

// ---------------------------------------------------------------------------
// Launch
// ---------------------------------------------------------------------------
extern "C" void kernel_launch(void* const* d_in, const int* in_sizes, int n_in,
                              void* d_out, int out_size, void* d_ws, size_t ws_size,
                              hipStream_t stream) {
    const float* x      = (const float*)d_in[0];
    const float* weight = (const float*)d_in[1];
    const float* bias   = (const float*)d_in[2];
    const float* fc1w   = (const float*)d_in[3];
    const float* fc1b   = (const float*)d_in[4];
    const float* fc2w   = (const float*)d_in[5];
    const float* fc2b   = (const float*)d_in[6];
    float* out = (float*)d_out;

    char* ws = (char*)d_ws;
    // workspace layout (256 B aligned)
    unsigned short* xt      = (unsigned short*)(ws);              // 55,115,776 B
    unsigned short* aggw    = (unsigned short*)(ws + 55115776);   // 37,748,736 B
    float*          partial = (float*)(ws + 92864512);            //  1,835,008 B
    float*          att     = (float*)(ws + 94699520);            //        512 B
    float*          aggb    = (float*)(ws + 94700032);            //     32,768 B

    transpose_pool_kernel<<<BB * HH, 256, 0, stream>>>(x, xt, partial);
    attn_kernel<<<BB, 256, 0, stream>>>(partial, fc1w, fc1b, fc2w, fc2b, att);
    aggw_kernel<<<COUT * 4, 256, 0, stream>>>(weight, bias, att, aggw, aggb);
    conv_gemm_kernel<<<BB * 25, 512, 0, stream>>>(xt, aggw, aggb, out);
}